// Round 5
// baseline (117.080 us; speedup 1.0000x reference)
//
#include <hip/hip_runtime.h>
#include <hip/hip_fp16.h>

#define NT 256
#define PPT 6

constexpr int TABLE_SZ = 721 * 1441;

// slim superquad: per level-0 cell, 32 B = {L0 quad, L1 quad} as 2 x uint4
// (4 corners x 2 feats, fp16 each). Levels 2+3 served from LDS vertex tables.
constexpr int QLAT = 181, QLON = 361;
constexpr int NCELLS = QLAT * QLON;            // 65341 cells -> 2.09 MB

// vertex tables for levels 2,3: fp16x2 per vertex (u32)
constexpr int VT2_C = 92, VT2_N = 47 * 92;     // 4324 verts (rows 0..46, cols 0..91)
constexpr int VT3_C = 47, VT3_N = 24 * 47;     // 1128 verts (rows 0..23, cols 0..46)
constexpr int VT_N  = VT2_N + VT3_N;           // 5452 u32 = 21.8 KB
constexpr int VT_N4 = VT_N / 4;                // 1363 uint4

// workspace layout (bytes)
constexpr size_t OFF_VT  = (size_t)NCELLS * 32;          // after superquad
constexpr size_t WS_NEED = OFF_VT + (size_t)VT_N * 4;    // ~2.11 MB

// per-(level,row) LUT: rows 181 + 91 + 46 + 23 = 341 entries of {ca, inv_n2}
constexpr int LUT_OFF1 = 181, LUT_OFF2 = 272, LUT_OFF3 = 318;
constexpr int LUT_N = 341;

typedef float v4f __attribute__((ext_vector_type(4)));
typedef float v2f __attribute__((ext_vector_type(2)));

__device__ __constant__ float c_s2_tab[4] = {0.008726535498f, 0.017452406437f,
                                             0.034899496703f, 0.069756473744f};

__global__ __launch_bounds__(256)
void build_tables(const float* __restrict__ emb,
                  uint4* __restrict__ sq,      // NCELLS * 2
                  uint*  __restrict__ vt)      // VT_N
{
    const int t = blockIdx.x * 256 + threadIdx.x;
    const float2* embv = (const float2*)emb;
    if (t < NCELLS) {
        const int la = t / QLON, lo = t - la * QLON;
        #pragma unroll
        for (int i = 0; i < 2; ++i) {
            const int width = 1440 >> i;
            const int ra = la >> i, co = lo >> i;   // level-i cell (floor identity)
            const float2* tb = embv + (size_t)i * TABLE_SZ;
            const float2 e0 = tb[ra * width + co];
            const float2 e1 = tb[ra * width + co + 1];
            const float2 e2 = tb[(ra + 1) * width + co];
            const float2 e3 = tb[(ra + 1) * width + co + 1];
            union { uint4 u; __half2 h[4]; } pk;
            pk.h[0] = __floats2half2_rn(e0.x, e0.y);
            pk.h[1] = __floats2half2_rn(e1.x, e1.y);
            pk.h[2] = __floats2half2_rn(e2.x, e2.y);
            pk.h[3] = __floats2half2_rn(e3.x, e3.y);
            sq[(size_t)t * 2 + i] = pk.u;
        }
    } else {
        const int u = t - NCELLS;
        if (u < VT_N) {
            float2 e;
            if (u < VT2_N) {
                const int rr = u / VT2_C, cc = u - rr * VT2_C;
                e = embv[(size_t)2 * TABLE_SZ + rr * 360 + cc];
            } else {
                const int v = u - VT2_N;
                const int rr = v / VT3_C, cc = v - rr * VT3_C;
                e = embv[(size_t)3 * TABLE_SZ + rr * 180 + cc];
            }
            union { uint uu; __half2 h; } pk;
            pk.h = __floats2half2_rn(e.x, e.y);
            vt[u] = pk.uu;
        }
    }
}

// ---- main kernel: levels 0+1 via 32 B global gather, levels 2+3 from LDS ----
__global__ __launch_bounds__(NT)
void ngp_interp(const float* __restrict__ x,
                const uint4* __restrict__ sq,
                const uint4* __restrict__ vtq,   // VT_N4 uint4
                float* __restrict__ out,
                int B)
{
    const float r = 0.017453292519943295f;   // pi/180 in fp32
    const float bmin_lat = -90.25f;
    const float bmin_lon = -0.25f;
    const float bmax_lat = 90.25f, bmax_lon = 360.25f;

    const int t = threadIdx.x;
    const int base = blockIdx.x * (NT * PPT) + t;

    // ---- issue all x loads FIRST: latency hides under the LDS fills ----
    v2f xp[PPT];
    #pragma unroll
    for (int k = 0; k < PPT; ++k) {
        const int p = base + k * NT;
        const int pc = p < B ? p : B - 1;          // clamp: safe full-wave read
        xp[k] = __builtin_nontemporal_load(reinterpret_cast<const v2f*>(x) + pc);
    }

    // ---- LDS: vertex tables for levels 2+3 (21.8 KB) ----
    __shared__ uint4 s_vt[VT_N4];
    for (int i = t; i < VT_N4; i += NT) s_vt[i] = vtq[i];

    // ---- tiny LUT: {ca, inv_n2} per (level, lat-row); bit-identical math ----
    __shared__ float2 lut[LUT_N];
    for (int i = t; i < LUT_N; i += NT) {
        int lv, row;
        if (i < LUT_OFF1)      { lv = 0; row = i; }
        else if (i < LUT_OFF2) { lv = 1; row = i - LUT_OFF1; }
        else if (i < LUT_OFF3) { lv = 2; row = i - LUT_OFF2; }
        else                   { lv = 3; row = i - LUT_OFF3; }
        const float gsl = (float)(1 << lv);
        const float gmin_lat = (float)row * gsl + bmin_lat;
        const float ca = fabsf(__cosf(gmin_lat * r));
        const float z2 = ca * c_s2_tab[lv];
        const float n2 = z2 + z2 * z2 * z2 * (1.0f / 6.0f);
        lut[i] = make_float2(ca, __builtin_amdgcn_rcpf(n2));
    }
    __syncthreads();

    const uint* vt2 = (const uint*)s_vt;
    const uint* vt3 = vt2 + VT2_N;

    // ---- compute cells + issue ALL gathers (12 outstanding per thread) ----
    float vlat[PPT], vlon[PPT];
    uint4 g0[PPT], g1[PPT];
    #pragma unroll
    for (int k = 0; k < PPT; ++k) {
        const float xlat = xp[k].x;
        const float xlon = xp[k].y;
        const float xc_lat = fminf(fmaxf(xlat, bmin_lat), bmax_lat);
        const float xc_lon = fminf(fmaxf(xlon, bmin_lon), bmax_lon);
        vlat[k] = xc_lat - bmin_lat;   // [0, 180.5]
        vlon[k] = xc_lon - bmin_lon;   // [0, 360.5]
        const int cell0 = (int)floorf(vlat[k]) * QLON + (int)floorf(vlon[k]);
        const uint4* cp = sq + (size_t)cell0 * 2;
        g0[k] = cp[0];
        g1[k] = cp[1];
    }

    // ---- per-point math + store ----
    #pragma unroll
    for (int k = 0; k < PPT; ++k) {
        const float xlat = xp[k].x;
        const float xlon = xp[k].y;
        const float v_lat = vlat[k];
        const float v_lon = vlon[k];

        float o[8];

        // weight helper: identical fp32 sequence to previous (verified) rounds
        auto weights = [&](float gs, float inv_gs, int lut_base,
                           float blat_f, float blon_f,
                           float& wlat, float& wlon) {
            const float gmin_lat = blat_f * gs + bmin_lat;
            const float gmin_lon = blon_f * gs + bmin_lon;
            const float gmax_lon = gmin_lon + gs;
            wlat = (xlat - gmin_lat) * inv_gs;
            const float2 cl = lut[lut_base + (int)blat_f];
            const float h1 = (gmax_lon - xlon) * r * 0.5f;       // <= 0.0699 rad
            const float s1 = h1 - h1 * h1 * h1 * (1.0f / 6.0f);  // sin(h1)
            const float z1 = cl.x * s1;
            const float n1 = z1 + z1 * z1 * z1 * (1.0f / 6.0f);  // asin(z1)
            wlon = n1 * cl.y;
        };
        auto bilerp = [](float2 f0, float2 f1, float2 f2, float2 f3,
                         float wlat, float wlon, float* dst) {
            const v2f E0 = {f0.x, f0.y}, E1 = {f1.x, f1.y};
            const v2f E2 = {f2.x, f2.y}, E3 = {f3.x, f3.y};
            const v2f wa = {wlat, wlat};
            const v2f wo = {wlon, wlon};
            const v2f c0 = E0 + (E2 - E0) * wa;
            const v2f c1 = E1 + (E3 - E1) * wa;
            const v2f res = c0 + (c1 - c0) * wo;
            dst[0] = res.x; dst[1] = res.y;
        };

        // ---- levels 0,1: quads from the 32 B global record ----
        #pragma unroll
        for (int i = 0; i < 2; ++i) {
            const float gs = (float)(1 << i);
            const float inv_gs = 1.0f / gs;
            const float blat_f = floorf(v_lat * inv_gs);
            const float blon_f = floorf(v_lon * inv_gs);
            float wlat, wlon;
            weights(gs, inv_gs, i == 0 ? 0 : LUT_OFF1, blat_f, blon_f, wlat, wlon);
            union { uint4 u; __half2 h[4]; } pk;
            pk.u = i == 0 ? g0[k] : g1[k];
            bilerp(__half22float2(pk.h[0]), __half22float2(pk.h[1]),
                   __half22float2(pk.h[2]), __half22float2(pk.h[3]),
                   wlat, wlon, &o[2 * i]);
        }

        // ---- level 2: verts from LDS ----
        {
            const float blat_f = floorf(v_lat * 0.25f);
            const float blon_f = floorf(v_lon * 0.25f);
            float wlat, wlon;
            weights(4.0f, 0.25f, LUT_OFF2, blat_f, blon_f, wlat, wlon);
            const int i2 = (int)blat_f * VT2_C + (int)blon_f;
            union { uint uu; __half2 h; } a0, a1, a2, a3;
            a0.uu = vt2[i2];            a1.uu = vt2[i2 + 1];
            a2.uu = vt2[i2 + VT2_C];    a3.uu = vt2[i2 + VT2_C + 1];
            bilerp(__half22float2(a0.h), __half22float2(a1.h),
                   __half22float2(a2.h), __half22float2(a3.h),
                   wlat, wlon, &o[4]);
        }
        // ---- level 3: verts from LDS ----
        {
            const float blat_f = floorf(v_lat * 0.125f);
            const float blon_f = floorf(v_lon * 0.125f);
            float wlat, wlon;
            weights(8.0f, 0.125f, LUT_OFF3, blat_f, blon_f, wlat, wlon);
            const int i3 = (int)blat_f * VT3_C + (int)blon_f;
            union { uint uu; __half2 h; } a0, a1, a2, a3;
            a0.uu = vt3[i3];            a1.uu = vt3[i3 + 1];
            a2.uu = vt3[i3 + VT3_C];    a3.uu = vt3[i3 + VT3_C + 1];
            bilerp(__half22float2(a0.h), __half22float2(a1.h),
                   __half22float2(a2.h), __half22float2(a3.h),
                   wlat, wlon, &o[6]);
        }

        const int p = base + k * NT;
        if (p < B) {
            v4f* op = reinterpret_cast<v4f*>(out + (size_t)p * 8);
            const v4f lo = {o[0], o[1], o[2], o[3]};
            const v4f hi = {o[4], o[5], o[6], o[7]};
            __builtin_nontemporal_store(lo, op);
            __builtin_nontemporal_store(hi, op + 1);
        }
    }
}

// ---- fallback (no workspace): single-point kernel, reads emb directly ----
__global__ __launch_bounds__(NT)
void ngp_interp_fb(const float* __restrict__ x,
                   const float* __restrict__ emb,
                   float* __restrict__ out,
                   int B)
{
    const float r = 0.017453292519943295f;
    const float bmin_lat = -90.25f;
    const float bmin_lon = -0.25f;

    __shared__ float2 lut[LUT_N];
    for (int t = threadIdx.x; t < LUT_N; t += NT) {
        int lvl, row;
        if (t < LUT_OFF1)      { lvl = 0; row = t; }
        else if (t < LUT_OFF2) { lvl = 1; row = t - LUT_OFF1; }
        else if (t < LUT_OFF3) { lvl = 2; row = t - LUT_OFF2; }
        else                   { lvl = 3; row = t - LUT_OFF3; }
        const float gs = (float)(1 << lvl);
        const float gmin_lat = (float)row * gs + bmin_lat;
        const float ca = fabsf(__cosf(gmin_lat * r));
        const float z2 = ca * c_s2_tab[lvl];
        const float n2 = z2 + z2 * z2 * z2 * (1.0f / 6.0f);
        lut[t] = make_float2(ca, __builtin_amdgcn_rcpf(n2));
    }
    __syncthreads();

    const int p = blockIdx.x * NT + threadIdx.x;
    if (p >= B) return;

    const v2f xp = __builtin_nontemporal_load(reinterpret_cast<const v2f*>(x) + p);
    const float xlat = xp.x;
    const float xlon = xp.y;

    const float bmax_lat = 90.25f, bmax_lon = 360.25f;
    const float xc_lat = fminf(fmaxf(xlat, bmin_lat), bmax_lat);
    const float xc_lon = fminf(fmaxf(xlon, bmin_lon), bmax_lon);
    const float v_lat = xc_lat - bmin_lat;
    const float v_lon = xc_lon - bmin_lon;

    const int lut_off[4] = {0, LUT_OFF1, LUT_OFF2, LUT_OFF3};
    float o[8];

    #pragma unroll
    for (int i = 0; i < 4; ++i) {
        const float gs     = (float)(1 << i);
        const float inv_gs = 1.0f / gs;
        const int   width  = 1440 >> i;

        const float blat_f = floorf(v_lat * inv_gs);
        const float blon_f = floorf(v_lon * inv_gs);
        const float gmin_lat = blat_f * gs + bmin_lat;
        const float gmin_lon = blon_f * gs + bmin_lon;
        const float gmax_lon = gmin_lon + gs;
        const int bl_lat = (int)blat_f;
        const int bl_lon = (int)blon_f;

        const int idx00 = bl_lat * width + bl_lon;
        const float* base0 = emb + ((size_t)i * TABLE_SZ + (size_t)idx00) * 2;
        const float* base1 = base0 + (size_t)width * 2;
        v4f eA, eB;
        __builtin_memcpy(&eA, base0, 16);
        __builtin_memcpy(&eB, base1, 16);
        const v2f E0 = {eA.x, eA.y}, E1 = {eA.z, eA.w};
        const v2f E2 = {eB.x, eB.y}, E3 = {eB.z, eB.w};

        const float wlat = (xlat - gmin_lat) * inv_gs;

        const float2 cl = lut[lut_off[i] + bl_lat];
        const float h1 = (gmax_lon - xlon) * r * 0.5f;
        const float s1 = h1 - h1 * h1 * h1 * (1.0f / 6.0f);
        const float z1 = cl.x * s1;
        const float n1 = z1 + z1 * z1 * z1 * (1.0f / 6.0f);
        const float wlon = n1 * cl.y;

        const v2f wa = {wlat, wlat};
        const v2f wo = {wlon, wlon};
        const v2f c0 = E0 + (E2 - E0) * wa;
        const v2f c1 = E1 + (E3 - E1) * wa;
        const v2f res = c0 + (c1 - c0) * wo;
        o[2*i]   = res.x;
        o[2*i+1] = res.y;
    }

    v4f* op = reinterpret_cast<v4f*>(out + (size_t)p * 8);
    const v4f lo = {o[0], o[1], o[2], o[3]};
    const v4f hi = {o[4], o[5], o[6], o[7]};
    __builtin_nontemporal_store(lo, op);
    __builtin_nontemporal_store(hi, op + 1);
}

extern "C" void kernel_launch(void* const* d_in, const int* in_sizes, int n_in,
                              void* d_out, int out_size, void* d_ws, size_t ws_size,
                              hipStream_t stream)
{
    const float* x   = (const float*)d_in[0];   // (B, 2) fp32
    const float* emb = (const float*)d_in[1];   // (4, TABLE, 2) fp32
    float* out = (float*)d_out;                 // (B, 8) fp32
    const int B = in_sizes[0] / 2;

    if (ws_size >= WS_NEED) {
        uint4* sq = (uint4*)d_ws;
        uint*  vt = (uint*)((char*)d_ws + OFF_VT);
        const int nbuild = NCELLS + VT_N;
        build_tables<<<(nbuild + 255) / 256, 256, 0, stream>>>(emb, sq, vt);
        const int pts_per_blk = NT * PPT;
        const int grid = (B + pts_per_blk - 1) / pts_per_blk;
        ngp_interp<<<grid, NT, 0, stream>>>(x, sq, (const uint4*)vt, out, B);
    } else {
        const int grid = (B + NT - 1) / NT;
        ngp_interp_fb<<<grid, NT, 0, stream>>>(x, emb, out, B);
    }
}

// Round 6
// 114.565 us; speedup vs baseline: 1.0220x; 1.0220x over previous
//
#include <hip/hip_runtime.h>
#include <hip/hip_fp16.h>

#define NT 256
#define PPT 4

constexpr int TABLE_SZ = 721 * 1441;

// slim superquad: per level-0 cell, 32 B = {L0 quad, L1 quad} as 2 x uint4
// (4 corners x 2 feats, fp16 each). Levels 2+3 served from LDS vertex tables.
constexpr int QLAT = 181, QLON = 361;
constexpr int NCELLS = QLAT * QLON;            // 65341 cells -> 2.09 MB

// vertex tables for levels 2,3: fp16x2 per vertex (u32)
constexpr int VT2_C = 92, VT2_N = 47 * 92;     // 4324 verts (rows 0..46, cols 0..91)
constexpr int VT3_C = 47, VT3_N = 24 * 47;     // 1128 verts (rows 0..23, cols 0..46)
constexpr int VT_N  = VT2_N + VT3_N;           // 5452 u32 = 21.8 KB
constexpr int VT_N4 = VT_N / 4;                // 1363 uint4

// workspace layout (bytes)
constexpr size_t OFF_VT  = (size_t)NCELLS * 32;          // after superquad
constexpr size_t WS_NEED = OFF_VT + (size_t)VT_N * 4;    // ~2.11 MB

// per-(level,row) LUT: rows 181 + 91 + 46 + 23 = 341 entries of {ca, inv_n2}
constexpr int LUT_OFF1 = 181, LUT_OFF2 = 272, LUT_OFF3 = 318;
constexpr int LUT_N = 341;

typedef float v4f __attribute__((ext_vector_type(4)));
typedef float v2f __attribute__((ext_vector_type(2)));

__device__ __constant__ float c_s2_tab[4] = {0.008726535498f, 0.017452406437f,
                                             0.034899496703f, 0.069756473744f};

__global__ __launch_bounds__(256)
void build_tables(const float* __restrict__ emb,
                  uint4* __restrict__ sq,      // NCELLS * 2
                  uint*  __restrict__ vt)      // VT_N
{
    const int t = blockIdx.x * 256 + threadIdx.x;
    const float2* embv = (const float2*)emb;
    if (t < NCELLS) {
        const int la = t / QLON, lo = t - la * QLON;
        #pragma unroll
        for (int i = 0; i < 2; ++i) {
            const int width = 1440 >> i;
            const int ra = la >> i, co = lo >> i;   // level-i cell (floor identity)
            const float2* tb = embv + (size_t)i * TABLE_SZ;
            const float2 e0 = tb[ra * width + co];
            const float2 e1 = tb[ra * width + co + 1];
            const float2 e2 = tb[(ra + 1) * width + co];
            const float2 e3 = tb[(ra + 1) * width + co + 1];
            union { uint4 u; __half2 h[4]; } pk;
            pk.h[0] = __floats2half2_rn(e0.x, e0.y);
            pk.h[1] = __floats2half2_rn(e1.x, e1.y);
            pk.h[2] = __floats2half2_rn(e2.x, e2.y);
            pk.h[3] = __floats2half2_rn(e3.x, e3.y);
            sq[(size_t)t * 2 + i] = pk.u;
        }
    } else {
        const int u = t - NCELLS;
        if (u < VT_N) {
            float2 e;
            if (u < VT2_N) {
                const int rr = u / VT2_C, cc = u - rr * VT2_C;
                e = embv[(size_t)2 * TABLE_SZ + rr * 360 + cc];
            } else {
                const int v = u - VT2_N;
                const int rr = v / VT3_C, cc = v - rr * VT3_C;
                e = embv[(size_t)3 * TABLE_SZ + rr * 180 + cc];
            }
            union { uint uu; __half2 h; } pk;
            pk.h = __floats2half2_rn(e.x, e.y);
            vt[u] = pk.uu;
        }
    }
}

// ---- main kernel: levels 0+1 via 32 B global gather, levels 2+3 from LDS ----
__global__ __launch_bounds__(NT)
void ngp_interp(const float* __restrict__ x,
                const uint4* __restrict__ sq,
                const uint4* __restrict__ vtq,   // VT_N4 uint4
                float* __restrict__ out,
                int B)
{
    const float r = 0.017453292519943295f;   // pi/180 in fp32
    const float bmin_lat = -90.25f;
    const float bmin_lon = -0.25f;
    const float bmax_lat = 90.25f, bmax_lon = 360.25f;

    const int t = threadIdx.x;
    const int base = blockIdx.x * (NT * PPT) + t;

    // ---- issue all x loads FIRST: latency hides under the LDS fills ----
    v2f xp[PPT];
    #pragma unroll
    for (int k = 0; k < PPT; ++k) {
        const int p = base + k * NT;
        const int pc = p < B ? p : B - 1;          // clamp: safe full-wave read
        xp[k] = __builtin_nontemporal_load(reinterpret_cast<const v2f*>(x) + pc);
    }

    // ---- LDS: vertex tables for levels 2+3 (21.8 KB) ----
    __shared__ uint4 s_vt[VT_N4];
    for (int i = t; i < VT_N4; i += NT) s_vt[i] = vtq[i];

    // ---- tiny LUT: {ca, inv_n2} per (level, lat-row); bit-identical math ----
    __shared__ float2 lut[LUT_N];
    for (int i = t; i < LUT_N; i += NT) {
        int lv, row;
        if (i < LUT_OFF1)      { lv = 0; row = i; }
        else if (i < LUT_OFF2) { lv = 1; row = i - LUT_OFF1; }
        else if (i < LUT_OFF3) { lv = 2; row = i - LUT_OFF2; }
        else                   { lv = 3; row = i - LUT_OFF3; }
        const float gsl = (float)(1 << lv);
        const float gmin_lat = (float)row * gsl + bmin_lat;
        const float ca = fabsf(__cosf(gmin_lat * r));
        const float z2 = ca * c_s2_tab[lv];
        const float n2 = z2 + z2 * z2 * z2 * (1.0f / 6.0f);
        lut[i] = make_float2(ca, __builtin_amdgcn_rcpf(n2));
    }
    __syncthreads();

    const uint* vt2 = (const uint*)s_vt;
    const uint* vt3 = vt2 + VT2_N;

    // ---- compute cells + issue ALL gathers (8 outstanding per thread) ----
    float vlat[PPT], vlon[PPT];
    uint4 g0[PPT], g1[PPT];
    #pragma unroll
    for (int k = 0; k < PPT; ++k) {
        const float xlat = xp[k].x;
        const float xlon = xp[k].y;
        const float xc_lat = fminf(fmaxf(xlat, bmin_lat), bmax_lat);
        const float xc_lon = fminf(fmaxf(xlon, bmin_lon), bmax_lon);
        vlat[k] = xc_lat - bmin_lat;   // [0, 180.5]
        vlon[k] = xc_lon - bmin_lon;   // [0, 360.5]
        const int cell0 = (int)floorf(vlat[k]) * QLON + (int)floorf(vlon[k]);
        const uint4* cp = sq + (size_t)cell0 * 2;
        g0[k] = cp[0];
        g1[k] = cp[1];
    }

    // ---- per-point math + store ----
    #pragma unroll
    for (int k = 0; k < PPT; ++k) {
        const float xlat = xp[k].x;
        const float xlon = xp[k].y;
        const float v_lat = vlat[k];
        const float v_lon = vlon[k];

        float o[8];

        // weight helper: identical fp32 sequence to previous (verified) rounds
        auto weights = [&](float gs, float inv_gs, int lut_base,
                           float blat_f, float blon_f,
                           float& wlat, float& wlon) {
            const float gmin_lat = blat_f * gs + bmin_lat;
            const float gmin_lon = blon_f * gs + bmin_lon;
            const float gmax_lon = gmin_lon + gs;
            wlat = (xlat - gmin_lat) * inv_gs;
            const float2 cl = lut[lut_base + (int)blat_f];
            const float h1 = (gmax_lon - xlon) * r * 0.5f;       // <= 0.0699 rad
            const float s1 = h1 - h1 * h1 * h1 * (1.0f / 6.0f);  // sin(h1)
            const float z1 = cl.x * s1;
            const float n1 = z1 + z1 * z1 * z1 * (1.0f / 6.0f);  // asin(z1)
            wlon = n1 * cl.y;
        };
        auto bilerp = [](float2 f0, float2 f1, float2 f2, float2 f3,
                         float wlat, float wlon, float* dst) {
            const v2f E0 = {f0.x, f0.y}, E1 = {f1.x, f1.y};
            const v2f E2 = {f2.x, f2.y}, E3 = {f3.x, f3.y};
            const v2f wa = {wlat, wlat};
            const v2f wo = {wlon, wlon};
            const v2f c0 = E0 + (E2 - E0) * wa;
            const v2f c1 = E1 + (E3 - E1) * wa;
            const v2f res = c0 + (c1 - c0) * wo;
            dst[0] = res.x; dst[1] = res.y;
        };

        // ---- levels 0,1: quads from the 32 B global record ----
        #pragma unroll
        for (int i = 0; i < 2; ++i) {
            const float gs = (float)(1 << i);
            const float inv_gs = 1.0f / gs;
            const float blat_f = floorf(v_lat * inv_gs);
            const float blon_f = floorf(v_lon * inv_gs);
            float wlat, wlon;
            weights(gs, inv_gs, i == 0 ? 0 : LUT_OFF1, blat_f, blon_f, wlat, wlon);
            union { uint4 u; __half2 h[4]; } pk;
            pk.u = i == 0 ? g0[k] : g1[k];
            bilerp(__half22float2(pk.h[0]), __half22float2(pk.h[1]),
                   __half22float2(pk.h[2]), __half22float2(pk.h[3]),
                   wlat, wlon, &o[2 * i]);
        }

        // ---- level 2: verts from LDS ----
        {
            const float blat_f = floorf(v_lat * 0.25f);
            const float blon_f = floorf(v_lon * 0.25f);
            float wlat, wlon;
            weights(4.0f, 0.25f, LUT_OFF2, blat_f, blon_f, wlat, wlon);
            const int i2 = (int)blat_f * VT2_C + (int)blon_f;
            union { uint uu; __half2 h; } a0, a1, a2, a3;
            a0.uu = vt2[i2];            a1.uu = vt2[i2 + 1];
            a2.uu = vt2[i2 + VT2_C];    a3.uu = vt2[i2 + VT2_C + 1];
            bilerp(__half22float2(a0.h), __half22float2(a1.h),
                   __half22float2(a2.h), __half22float2(a3.h),
                   wlat, wlon, &o[4]);
        }
        // ---- level 3: verts from LDS ----
        {
            const float blat_f = floorf(v_lat * 0.125f);
            const float blon_f = floorf(v_lon * 0.125f);
            float wlat, wlon;
            weights(8.0f, 0.125f, LUT_OFF3, blat_f, blon_f, wlat, wlon);
            const int i3 = (int)blat_f * VT3_C + (int)blon_f;
            union { uint uu; __half2 h; } a0, a1, a2, a3;
            a0.uu = vt3[i3];            a1.uu = vt3[i3 + 1];
            a2.uu = vt3[i3 + VT3_C];    a3.uu = vt3[i3 + VT3_C + 1];
            bilerp(__half22float2(a0.h), __half22float2(a1.h),
                   __half22float2(a2.h), __half22float2(a3.h),
                   wlat, wlon, &o[6]);
        }

        const int p = base + k * NT;
        if (p < B) {
            v4f* op = reinterpret_cast<v4f*>(out + (size_t)p * 8);
            const v4f lo = {o[0], o[1], o[2], o[3]};
            const v4f hi = {o[4], o[5], o[6], o[7]};
            __builtin_nontemporal_store(lo, op);
            __builtin_nontemporal_store(hi, op + 1);
        }
    }
}

// ---- fallback (no workspace): single-point kernel, reads emb directly ----
__global__ __launch_bounds__(NT)
void ngp_interp_fb(const float* __restrict__ x,
                   const float* __restrict__ emb,
                   float* __restrict__ out,
                   int B)
{
    const float r = 0.017453292519943295f;
    const float bmin_lat = -90.25f;
    const float bmin_lon = -0.25f;

    __shared__ float2 lut[LUT_N];
    for (int t = threadIdx.x; t < LUT_N; t += NT) {
        int lvl, row;
        if (t < LUT_OFF1)      { lvl = 0; row = t; }
        else if (t < LUT_OFF2) { lvl = 1; row = t - LUT_OFF1; }
        else if (t < LUT_OFF3) { lvl = 2; row = t - LUT_OFF2; }
        else                   { lvl = 3; row = t - LUT_OFF3; }
        const float gs = (float)(1 << lvl);
        const float gmin_lat = (float)row * gs + bmin_lat;
        const float ca = fabsf(__cosf(gmin_lat * r));
        const float z2 = ca * c_s2_tab[lvl];
        const float n2 = z2 + z2 * z2 * z2 * (1.0f / 6.0f);
        lut[t] = make_float2(ca, __builtin_amdgcn_rcpf(n2));
    }
    __syncthreads();

    const int p = blockIdx.x * NT + threadIdx.x;
    if (p >= B) return;

    const v2f xp = __builtin_nontemporal_load(reinterpret_cast<const v2f*>(x) + p);
    const float xlat = xp.x;
    const float xlon = xp.y;

    const float bmax_lat = 90.25f, bmax_lon = 360.25f;
    const float xc_lat = fminf(fmaxf(xlat, bmin_lat), bmax_lat);
    const float xc_lon = fminf(fmaxf(xlon, bmin_lon), bmax_lon);
    const float v_lat = xc_lat - bmin_lat;
    const float v_lon = xc_lon - bmin_lon;

    const int lut_off[4] = {0, LUT_OFF1, LUT_OFF2, LUT_OFF3};
    float o[8];

    #pragma unroll
    for (int i = 0; i < 4; ++i) {
        const float gs     = (float)(1 << i);
        const float inv_gs = 1.0f / gs;
        const int   width  = 1440 >> i;

        const float blat_f = floorf(v_lat * inv_gs);
        const float blon_f = floorf(v_lon * inv_gs);
        const float gmin_lat = blat_f * gs + bmin_lat;
        const float gmin_lon = blon_f * gs + bmin_lon;
        const float gmax_lon = gmin_lon + gs;
        const int bl_lat = (int)blat_f;
        const int bl_lon = (int)blon_f;

        const int idx00 = bl_lat * width + bl_lon;
        const float* base0 = emb + ((size_t)i * TABLE_SZ + (size_t)idx00) * 2;
        const float* base1 = base0 + (size_t)width * 2;
        v4f eA, eB;
        __builtin_memcpy(&eA, base0, 16);
        __builtin_memcpy(&eB, base1, 16);
        const v2f E0 = {eA.x, eA.y}, E1 = {eA.z, eA.w};
        const v2f E2 = {eB.x, eB.y}, E3 = {eB.z, eB.w};

        const float wlat = (xlat - gmin_lat) * inv_gs;

        const float2 cl = lut[lut_off[i] + bl_lat];
        const float h1 = (gmax_lon - xlon) * r * 0.5f;
        const float s1 = h1 - h1 * h1 * h1 * (1.0f / 6.0f);
        const float z1 = cl.x * s1;
        const float n1 = z1 + z1 * z1 * z1 * (1.0f / 6.0f);
        const float wlon = n1 * cl.y;

        const v2f wa = {wlat, wlat};
        const v2f wo = {wlon, wlon};
        const v2f c0 = E0 + (E2 - E0) * wa;
        const v2f c1 = E1 + (E3 - E1) * wa;
        const v2f res = c0 + (c1 - c0) * wo;
        o[2*i]   = res.x;
        o[2*i+1] = res.y;
    }

    v4f* op = reinterpret_cast<v4f*>(out + (size_t)p * 8);
    const v4f lo = {o[0], o[1], o[2], o[3]};
    const v4f hi = {o[4], o[5], o[6], o[7]};
    __builtin_nontemporal_store(lo, op);
    __builtin_nontemporal_store(hi, op + 1);
}

extern "C" void kernel_launch(void* const* d_in, const int* in_sizes, int n_in,
                              void* d_out, int out_size, void* d_ws, size_t ws_size,
                              hipStream_t stream)
{
    const float* x   = (const float*)d_in[0];   // (B, 2) fp32
    const float* emb = (const float*)d_in[1];   // (4, TABLE, 2) fp32
    float* out = (float*)d_out;                 // (B, 8) fp32
    const int B = in_sizes[0] / 2;

    if (ws_size >= WS_NEED) {
        uint4* sq = (uint4*)d_ws;
        uint*  vt = (uint*)((char*)d_ws + OFF_VT);
        const int nbuild = NCELLS + VT_N;
        build_tables<<<(nbuild + 255) / 256, 256, 0, stream>>>(emb, sq, vt);
        const int pts_per_blk = NT * PPT;
        const int grid = (B + pts_per_blk - 1) / pts_per_blk;
        ngp_interp<<<grid, NT, 0, stream>>>(x, sq, (const uint4*)vt, out, B);
    } else {
        const int grid = (B + NT - 1) / NT;
        ngp_interp_fb<<<grid, NT, 0, stream>>>(x, emb, out, B);
    }
}